// Round 15
// baseline (5731.059 us; speedup 1.0000x reference)
//
#include <hip/hip_runtime.h>
#include <stdint.h>

#define S_LEN 512
#define NB    64
#define HID   256
#define G3    768
#define SB    32768   // S_LEN * NB
#define NLAYER 6

typedef short bf16x8 __attribute__((ext_vector_type(8)));
typedef short bf16x4 __attribute__((ext_vector_type(4)));
typedef float floatx4 __attribute__((ext_vector_type(4)));
typedef unsigned short u16;
typedef unsigned int   u32;

__device__ __forceinline__ float bf2f(u16 v) {
  u32 u = ((u32)v) << 16;
  return __builtin_bit_cast(float, u);
}
__device__ __forceinline__ u16 f2bf(float f) {
  u32 u = __builtin_bit_cast(u32, f);
  u = (u + 0x7FFFu + ((u >> 16) & 1u)) >> 16;
  return (u16)u;
}
__device__ __forceinline__ float fsigmoid(float x) {
  return __builtin_amdgcn_rcpf(1.0f + __expf(-x));
}
__device__ __forceinline__ float ftanh(float x) {
  return 1.0f - 2.0f * __builtin_amdgcn_rcpf(1.0f + __expf(x + x));
}

// LDS-only barrier: order LDS writes across waves WITHOUT draining vmcnt.
__device__ __forceinline__ void lds_barrier() {
  asm volatile("s_waitcnt lgkmcnt(0)\n\ts_barrier" ::: "memory");
}

// ---------------------------------------------------------------------------
// detect_fp32 (multi-block): count bf16 NaN/Inf exponent patterns into *cnt
// (zero-initialized via hipMemsetAsync). fp32 input -> ~1000 hits in sample;
// genuine bf16 -> 0. Consumers test (*cnt > 64). Accumulation across bench
// replays cannot flip the boolean in either direction (0 stays 0; big grows).
// ---------------------------------------------------------------------------
__global__ void detect_fp32(const u16* __restrict__ x, int n, int* cnt) {
  int c = 0;
  const int stride = gridDim.x * blockDim.x;
  for (int i = blockIdx.x * blockDim.x + threadIdx.x; i < n; i += stride) {
    u16 v = x[i];
    if (((v >> 7) & 0xFF) == 0xFF) ++c;
  }
  if (c) atomicAdd(cnt, c);   // compiler coalesces to per-wave atomic
}

// cvt_all: fused conversion of all 7 inputs (fp32 or bf16 per count) into
// packed bf16 workspace copies. blockIdx.y selects the segment.
struct CvtArgs {
  const void* src[7];
  u16*        dst[7];
  int         n[7];
};
__global__ void cvt_all(CvtArgs a, const int* __restrict__ cnt) {
  const bool isf32 = (*cnt > 64);
  const int seg = blockIdx.y;
  const void* src = a.src[seg];
  u16*        dst = a.dst[seg];
  const int   n   = a.n[seg];
  const int stride = gridDim.x * blockDim.x;
  for (int i = blockIdx.x * blockDim.x + threadIdx.x; i < n; i += stride) {
    if (isf32) dst[i] = f2bf(((const float*)src)[i]);
    else       dst[i] = ((const u16*)src)[i];
  }
}

// prep_bias: combined gemm bias (f32): b_ih + (n<512 ? b_hh : 0).
__global__ void prep_bias(const u16* __restrict__ bih, const u16* __restrict__ bhh,
                          float* __restrict__ bc, int n) {
  int i = blockIdx.x * blockDim.x + threadIdx.x;
  if (i >= n) return;
  int col = i % G3;
  float v = bf2f(bih[i]);
  if (col < 512) v += bf2f(bhh[i]);
  bc[i] = v;
}

// write_out: fp32 staging -> d_out in the harness's output dtype per count.
__global__ void write_out(const float* __restrict__ hNs, void* __restrict__ out,
                          int n, const int* __restrict__ cnt) {
  int i = blockIdx.x * blockDim.x + threadIdx.x;
  if (i >= n) return;
  if (*cnt > 64) ((float*)out)[i] = hNs[i];
  else           ((u16*)out)[i]   = f2bf(hNs[i]);
}

// ---------------------------------------------------------------------------
// gate_gemm: gates = A @ W^T + bias, written in scan-native layout:
//   gateX[dir][bg(4)][s(512)][jcol(256)][gate(3)][b_in(16)]  (u16)
// A: [SB][K] bf16. 128x128 tile / WG, BK=64, XOR-swizzled LDS.
// ---------------------------------------------------------------------------
__global__ __launch_bounds__(256)
void gate_gemm(const u16* __restrict__ A, const u16* __restrict__ W,
               const float* __restrict__ bias, u16* __restrict__ outg, int K) {
  const int m0  = blockIdx.x * 128;
  const int n0  = blockIdx.y * 128;
  const int dir = blockIdx.z;
  W    += (size_t)dir * G3 * K;
  bias += (size_t)dir * G3;
  outg += (size_t)dir * (size_t)SB * G3;

  __shared__ __align__(16) u16 lA[8192];   // 128 rows x 64 k, chunk-swizzled
  __shared__ __align__(16) u16 lB[8192];

  const int tid  = threadIdx.x;
  const int lane = tid & 63;
  const int wv   = tid >> 6;
  const int wm   = wv & 1, wn = wv >> 1;
  const int l15  = lane & 15, quad = lane >> 4;

  floatx4 acc[4][4] = {};   // [mt][nt]

  for (int k0 = 0; k0 < K; k0 += 64) {
    bf16x8 ra[4], rb[4];
#pragma unroll
    for (int i = 0; i < 4; ++i) {
      int c   = i * 256 + tid;          // chunk 0..1023
      int row = c >> 3;
      int kc  = (c & 7) ^ (row & 7);    // XOR-swizzled source chunk
      ra[i] = *(const bf16x8*)(A + (size_t)(m0 + row) * K + (k0 + kc * 8));
      rb[i] = *(const bf16x8*)(W + (size_t)(n0 + row) * K + (k0 + kc * 8));
    }
    __syncthreads();   // previous tile's LDS reads complete
#pragma unroll
    for (int i = 0; i < 4; ++i) {
      *(bf16x8*)(lA + (size_t)(i * 256 + tid) * 8) = ra[i];
      *(bf16x8*)(lB + (size_t)(i * 256 + tid) * 8) = rb[i];
    }
    __syncthreads();

#pragma unroll
    for (int kt = 0; kt < 2; ++kt) {
      bf16x8 af[4], bfr[4];
#pragma unroll
      for (int mt = 0; mt < 4; ++mt) {
        int row = wm * 64 + mt * 16 + l15;
        int ch  = row * 8 + ((kt * 4 + quad) ^ (row & 7));
        af[mt] = *(const bf16x8*)(lA + ch * 8);
      }
#pragma unroll
      for (int nt = 0; nt < 4; ++nt) {
        int row = wn * 64 + nt * 16 + l15;
        int ch  = row * 8 + ((kt * 4 + quad) ^ (row & 7));
        bfr[nt] = *(const bf16x8*)(lB + ch * 8);
      }
#pragma unroll
      for (int mt = 0; mt < 4; ++mt)
#pragma unroll
        for (int nt = 0; nt < 4; ++nt)
          acc[mt][nt] = __builtin_amdgcn_mfma_f32_16x16x32_bf16(
              af[mt], bfr[nt], acc[mt][nt], 0, 0, 0);
    }
  }

  // epilogue: C/D col(n)=l15, row(m)=quad*4+r. m = s*64 + b_global where
  // s = m0/64 + wm, bg = mt, b_in = quad*4+r.
  const int sIdx = (m0 >> 6) + wm;
#pragma unroll
  for (int nt = 0; nt < 4; ++nt) {
    int n    = n0 + wn * 64 + nt * 16 + l15;
    int g    = n >> 8, jc = n & 255;
    float bv = bias[n];
#pragma unroll
    for (int mt = 0; mt < 4; ++mt) {
      bf16x4 pk;
#pragma unroll
      for (int r = 0; r < 4; ++r) pk[r] = (short)f2bf(acc[mt][nt][r] + bv);
      *(bf16x4*)(outg + ((((size_t)mt * 512 + sIdx) * 256 + jc) * 3 + g) * 16 +
                 quad * 4) = pk;
    }
  }
}

// ---------------------------------------------------------------------------
// gru_scan v16 == v9/v15 structure (the measured best: 773 us/layer) with one
// structure-preserving hint: #pragma unroll 2 on the t-loop, so cur/nxt are
// compile-time per copy and the hb2[cur] bases become loop-invariant.
// Ledger of measured-worse intrusions (do NOT reintroduce):
//   v10/v13 cvt_pk+packed-h -> +33-38% stall; v11/v12 asm exp -> corruption;
//   v14 s_setprio -> +23% (region split; 1 WG/CU so no role diversity).
// Structure: 44/48 weight frags register-resident (128 AGPR + 48 arch VGPR),
// 48 KB LDS (32 KB W_hn k-tail + 16 KB h double-buffer), one LDS-only
// barrier per step, gateX/layerOut vmcnt traffic in flight across it.
// ---------------------------------------------------------------------------
__global__ __launch_bounds__(512)
__attribute__((amdgpu_waves_per_eu(2, 2)))
void gru_scan(const u16* __restrict__ gateX,   // [2][4][512][256][3][16] bf16
              const u16* __restrict__ Whh,     // [2][768][256] (this layer)
              const u16* __restrict__ Bhh,     // [2][768]
              const u16* __restrict__ H0,      // [12][64][256] bf16 copy
              u16* __restrict__ layerOut,      // [SB][512] bf16
              float* __restrict__ hNs,         // fp32 staging [12][64][256]
              int layer) {
  const int dir = blockIdx.x & 1;
  const int bg  = blockIdx.x >> 1;
  const int tid = threadIdx.x;
  const int lane = tid & 63;
  const int wv   = tid >> 6;           // 0..7: owns hidden units [wv*32, wv*32+32)
  const int l15  = lane & 15, quad = lane >> 4;

  // 32 KB W_hn tail (k in [192,256)) + 16 KB h double-buffer = 48 KB
  __shared__ __align__(16) u16 wnL[16384];     // [kchunk(8)][n(256)][8]
  __shared__ __align__(16) u16 hb2[2][4096];   // [jchunk(32)][b(16)][8]

  const u16* Wd = Whh + (size_t)dir * G3 * HID;

  // --- prologue: W_hn k-tail -> LDS chunk-major (once) ---
#pragma unroll
  for (int i = 0; i < 4; ++i) {
    int ci = i * 512 + tid;            // 2048 bf16x8 chunks: 256 n x 8 kc
    int n  = ci >> 3;
    int kc = ci & 7;                   // local k-chunk; global = 24 + kc
    bf16x8 v = *(const bf16x8*)(Wd + (size_t)(512 + n) * HID + (24 + kc) * 8);
    *(bf16x8*)(wnL + kc * 2048 + n * 8) = v;
  }

  // --- stationary weights: r,z all kt (32 frags) + n kt=0..5 (12 frags) ---
  bf16x8 wrz[8][2][2];   // [kt][gate 0=r 1=z][nt]
  bf16x8 wn6[6][2];      // [kt 0..5][nt]
#pragma unroll
  for (int g = 0; g < 2; ++g)
#pragma unroll
    for (int nt = 0; nt < 2; ++nt) {
      int n = g * 256 + wv * 32 + nt * 16 + l15;
#pragma unroll
      for (int kt = 0; kt < 8; ++kt)
        wrz[kt][g][nt] = *(const bf16x8*)(Wd + (size_t)n * HID + kt * 32 + quad * 8);
    }
#pragma unroll
  for (int nt = 0; nt < 2; ++nt) {
    int n = 512 + wv * 32 + nt * 16 + l15;
#pragma unroll
    for (int kt = 0; kt < 6; ++kt)
      wn6[kt][nt] = *(const bf16x8*)(Wd + (size_t)n * HID + kt * 32 + quad * 8);
  }
#pragma unroll
  for (int kt = 0; kt < 8; ++kt)
#pragma unroll
    for (int g = 0; g < 2; ++g)
#pragma unroll
      for (int nt = 0; nt < 2; ++nt)
        asm volatile("" : "+v"(wrz[kt][g][nt]));
#pragma unroll
  for (int kt = 0; kt < 6; ++kt)
#pragma unroll
    for (int nt = 0; nt < 2; ++nt)
      asm volatile("" : "+v"(wn6[kt][nt]));

  float bhn[2];
#pragma unroll
  for (int nt = 0; nt < 2; ++nt)
    bhn[nt] = bf2f(Bhh[dir * G3 + 512 + wv * 32 + nt * 16 + l15]);

  const int mrow = quad * 4;           // first of this lane's 4 batch rows
  const int b0   = bg * 16 + mrow;     // global batch row at r=0

  // loop-invariant LDS bases (u16 indices)
  const int afb = quad * 128 + l15 * 8;                 // + kt*512
  const int bnb = quad * 2048 + (wv * 32 + l15) * 8;    // + (kt-6)*8192, +nt*128
  int wb[2];                                            // gate write/read base
#pragma unroll
  for (int nt = 0; nt < 2; ++nt)
    wb[nt] = (wv * 4 + nt * 2 + (l15 >> 3)) * 128 + quad * 32 + (l15 & 7);

  // --- init h in LDS chunk-major ---
  {
    int row = tid >> 5, slot = tid & 31;   // row=batch, slot=j-chunk
    const u16* hp = H0 + ((size_t)(layer * 2 + dir) * NB + bg * 16 + row) * HID + slot * 8;
    *(bf16x8*)(&hb2[0][slot * 128 + row * 8]) = *(const bf16x8*)hp;
  }

  // --- gateX pointer: one base, imm offsets ---
  const long sstep = dir ? -(long)(256 * 3 * 16) : (long)(256 * 3 * 16);
  const u16* xb;
  {
    const int s0 = dir ? (S_LEN - 1) : 0;
    xb = gateX + (size_t)dir * SB * G3 +
         ((((size_t)bg * 512 + s0) * 256 + (wv * 32 + l15)) * 3) * 16 + quad * 4;
  }
  bf16x4 xp[3][2];
#pragma unroll
  for (int g = 0; g < 3; ++g)
#pragma unroll
    for (int nt = 0; nt < 2; ++nt)
      xp[g][nt] = *(const bf16x4*)(xb + nt * 768 + g * 16);
  xb += sstep;

  // layerOut cooperative-store pointer: iteration t>0 stores h_{t-1} at s(t-1)
  u16* loPtr;
  {
    int row = tid >> 5, slot = tid & 31;
    const int sFirst = dir ? (S_LEN - 1) : 0;
    loPtr = layerOut + ((size_t)sFirst * NB + bg * 16 + row) * 512 +
            dir * HID + slot * 8;
  }
  const long lostep = dir ? -(long)(NB * 512) : (long)(NB * 512);

  lds_barrier();   // W_hn tail + h visible to all waves

#pragma unroll 2
  for (int t = 0; t < S_LEN; ++t) {
    const int cur = t & 1, nxt = cur ^ 1;

    // consume xpre: r/z (bias folded by gemm) -> acc init; xn kept bf16
    floatx4 aR[2], aZ[2], aN[2];
    bf16x4 xn0 = xp[2][0], xn1 = xp[2][1];
#pragma unroll
    for (int nt = 0; nt < 2; ++nt)
#pragma unroll
      for (int r = 0; r < 4; ++r) {
        aR[nt][r] = bf2f((u16)xp[0][nt][r]);
        aZ[nt][r] = bf2f((u16)xp[1][nt][r]);
        aN[nt][r] = bhn[nt];
      }

    // next step's prefetch; stays in flight across the lds_barrier
#pragma unroll
    for (int g = 0; g < 3; ++g)
#pragma unroll
      for (int nt = 0; nt < 2; ++nt)
        xp[g][nt] = *(const bf16x4*)(xb + nt * 768 + g * 16);
    if (t < S_LEN - 1) xb += sstep;

    // h_prev scalar reads from hb2[cur] (same addresses the gate phase writes)
    u16 hp[2][4];
#pragma unroll
    for (int nt = 0; nt < 2; ++nt)
#pragma unroll
      for (int r = 0; r < 4; ++r)
        hp[nt][r] = hb2[cur][wb[nt] + r * 8];

    // one-step-delayed cooperative layerOut store: h_{t-1} -> s(t-1)
    if (t > 0) {
      int row = tid >> 5, slot = tid & 31;
      bf16x8 hv = *(const bf16x8*)(&hb2[cur][slot * 128 + row * 8]);
      *(bf16x8*)loPtr = hv;   // fire-and-forget
      loPtr += lostep;
    }

    // MFMA phase: r,z and n(kt<6) B-frags from regs; n(kt 6,7) from LDS
#pragma unroll
    for (int kt = 0; kt < 8; ++kt) {
      bf16x8 af = *(const bf16x8*)(&hb2[cur][afb + kt * 512]);
      bf16x8 bn0, bn1;
      if (kt < 6) {
        bn0 = wn6[kt][0];
        bn1 = wn6[kt][1];
      } else {
        bn0 = *(const bf16x8*)(wnL + bnb + (kt - 6) * 8192);
        bn1 = *(const bf16x8*)(wnL + bnb + (kt - 6) * 8192 + 128);
      }
      aR[0] = __builtin_amdgcn_mfma_f32_16x16x32_bf16(af, wrz[kt][0][0], aR[0], 0, 0, 0);
      aR[1] = __builtin_amdgcn_mfma_f32_16x16x32_bf16(af, wrz[kt][0][1], aR[1], 0, 0, 0);
      aZ[0] = __builtin_amdgcn_mfma_f32_16x16x32_bf16(af, wrz[kt][1][0], aZ[0], 0, 0, 0);
      aZ[1] = __builtin_amdgcn_mfma_f32_16x16x32_bf16(af, wrz[kt][1][1], aZ[1], 0, 0, 0);
      aN[0] = __builtin_amdgcn_mfma_f32_16x16x32_bf16(af, bn0,           aN[0], 0, 0, 0);
      aN[1] = __builtin_amdgcn_mfma_f32_16x16x32_bf16(af, bn1,           aN[1], 0, 0, 0);
    }

    // gate phase: on accumulator fragments; h_prev from hp (bf16 scalars)
#pragma unroll
    for (int nt = 0; nt < 2; ++nt) {
      const bf16x4 xn = nt ? xn1 : xn0;
#pragma unroll
      for (int r = 0; r < 4; ++r) {
        float rg = fsigmoid(aR[nt][r]);
        float zg = fsigmoid(aZ[nt][r]);
        float ng = ftanh(bf2f((u16)xn[r]) + rg * aN[nt][r]);
        float h0 = bf2f(hp[nt][r]);
        float hn = ng + zg * (h0 - ng);
        hb2[nxt][wb[nt] + r * 8] = f2bf(hn);
      }
    }

    lds_barrier();   // h[nxt] visible; vmcnt traffic stays in flight
  }

  // final layerOut store + hNs: h_{511} is in hb2[0] (t=511: nxt=0)
  {
    int row = tid >> 5, slot = tid & 31;
    const int sLast = dir ? 0 : (S_LEN - 1);
    bf16x8 hv = *(const bf16x8*)(&hb2[0][slot * 128 + row * 8]);
    *(bf16x8*)(layerOut + ((size_t)sLast * NB + bg * 16 + row) * 512 +
               dir * HID + slot * 8) = hv;
    float* dst = hNs + ((size_t)(layer * 2 + dir) * NB + bg * 16 + row) * HID + slot * 8;
    floatx4 v0, v1;
#pragma unroll
    for (int i = 0; i < 4; ++i) v0[i] = bf2f((u16)hv[i]);
#pragma unroll
    for (int i = 0; i < 4; ++i) v1[i] = bf2f((u16)hv[4 + i]);
    *(floatx4*)dst = v0;
    *((floatx4*)dst + 1) = v1;
  }
}

// ---------------------------------------------------------------------------
extern "C" void kernel_launch(void* const* d_in, const int* in_sizes, int n_in,
                              void* d_out, int out_size, void* d_ws, size_t ws_size,
                              hipStream_t stream) {
  (void)n_in; (void)ws_size;
  char* ws = (char*)d_ws;
  int*   flag  = (int*)ws;
  float* hNs   = (float*)(ws + 4096);
  float* biasC = (float*)(ws + 790528);
  u16*   h0C   = (u16*)(ws + (1u << 20));
  u16*   wih0C = h0C   + 196608;
  u16*   wihC  = wih0C + 196608;
  u16*   whhC  = wihC  + 3932160;
  u16*   bihC  = whhC  + 2359296;
  u16*   bhhC  = bihC  + 9216;
  u16*   gateX = (u16*)(ws + (16u  << 20));
  u16*   bufA  = (u16*)(ws + (112u << 20));
  u16*   bufB  = (u16*)(ws + (144u << 20));
  u16*   xC    = bufB;   // aliased; layer-0 gemm reads it before bufB written

  hipMemsetAsync(flag, 0, 4, stream);
  detect_fp32<<<64, 256, 0, stream>>>((const u16*)d_in[0], 262144, flag);

  CvtArgs a;
  a.src[0] = d_in[0]; a.dst[0] = xC;    a.n[0] = in_sizes[0];
  a.src[1] = d_in[1]; a.dst[1] = h0C;   a.n[1] = in_sizes[1];
  a.src[2] = d_in[2]; a.dst[2] = wih0C; a.n[2] = in_sizes[2];
  a.src[3] = d_in[3]; a.dst[3] = wihC;  a.n[3] = in_sizes[3];
  a.src[4] = d_in[4]; a.dst[4] = whhC;  a.n[4] = in_sizes[4];
  a.src[5] = d_in[5]; a.dst[5] = bihC;  a.n[5] = in_sizes[5];
  a.src[6] = d_in[6]; a.dst[6] = bhhC;  a.n[6] = in_sizes[6];
  cvt_all<<<dim3(512, 7), 256, 0, stream>>>(a, flag);

  prep_bias<<<36, 256, 0, stream>>>(bihC, bhhC, biasC, NLAYER * 2 * G3);

  for (int layer = 0; layer < NLAYER; ++layer) {
    const u16* inp = (layer == 0) ? xC : ((layer & 1) ? bufA : bufB);
    u16* outBuf    = (layer & 1) ? bufB : bufA;

    const int K = (layer == 0) ? 128 : 512;
    const u16* W = (layer == 0) ? wih0C
                                : (wihC + (size_t)(layer - 1) * 2 * G3 * 512);
    dim3 grid(256, 6, 2);
    gate_gemm<<<grid, 256, 0, stream>>>(inp, W, biasC + (size_t)layer * 2 * G3,
                                        gateX, K);
    gru_scan<<<8, 512, 0, stream>>>(gateX, whhC + (size_t)layer * 2 * G3 * HID,
                                    bhhC + (size_t)layer * 2 * G3, h0C,
                                    outBuf, hNs, layer);
  }
  write_out<<<(out_size + 255) / 256, 256, 0, stream>>>(hNs, d_out, out_size, flag);
}

// Round 16
// 5164.931 us; speedup vs baseline: 1.1096x; 1.1096x over previous
//
#include <hip/hip_runtime.h>
#include <stdint.h>

#define S_LEN 512
#define NB    64
#define HID   256
#define G3    768
#define SB    32768   // S_LEN * NB
#define NLAYER 6

typedef short bf16x8 __attribute__((ext_vector_type(8)));
typedef short bf16x4 __attribute__((ext_vector_type(4)));
typedef float floatx4 __attribute__((ext_vector_type(4)));
typedef unsigned short u16;
typedef unsigned int   u32;

__device__ __forceinline__ float bf2f(u16 v) {
  u32 u = ((u32)v) << 16;
  return __builtin_bit_cast(float, u);
}
__device__ __forceinline__ u16 f2bf(float f) {
  u32 u = __builtin_bit_cast(u32, f);
  u = (u + 0x7FFFu + ((u >> 16) & 1u)) >> 16;
  return (u16)u;
}
__device__ __forceinline__ float fsigmoid(float x) {
  return __builtin_amdgcn_rcpf(1.0f + __expf(-x));
}
__device__ __forceinline__ float ftanh(float x) {
  return 1.0f - 2.0f * __builtin_amdgcn_rcpf(1.0f + __expf(x + x));
}

// LDS-only barrier: order LDS writes across waves WITHOUT draining vmcnt.
__device__ __forceinline__ void lds_barrier() {
  asm volatile("s_waitcnt lgkmcnt(0)\n\ts_barrier" ::: "memory");
}

// ---------------------------------------------------------------------------
// detect_fp32 (multi-block): count bf16 NaN/Inf exponent patterns into *cnt
// (zero-initialized via hipMemsetAsync). fp32 input -> ~1000 hits in sample;
// genuine bf16 -> 0. Consumers test (*cnt > 64). Accumulation across bench
// replays cannot flip the boolean in either direction (0 stays 0; big grows).
// ---------------------------------------------------------------------------
__global__ void detect_fp32(const u16* __restrict__ x, int n, int* cnt) {
  int c = 0;
  const int stride = gridDim.x * blockDim.x;
  for (int i = blockIdx.x * blockDim.x + threadIdx.x; i < n; i += stride) {
    u16 v = x[i];
    if (((v >> 7) & 0xFF) == 0xFF) ++c;
  }
  if (c) atomicAdd(cnt, c);   // compiler coalesces to per-wave atomic
}

// cvt_all: fused conversion of all 7 inputs (fp32 or bf16 per count) into
// packed bf16 workspace copies. blockIdx.y selects the segment.
struct CvtArgs {
  const void* src[7];
  u16*        dst[7];
  int         n[7];
};
__global__ void cvt_all(CvtArgs a, const int* __restrict__ cnt) {
  const bool isf32 = (*cnt > 64);
  const int seg = blockIdx.y;
  const void* src = a.src[seg];
  u16*        dst = a.dst[seg];
  const int   n   = a.n[seg];
  const int stride = gridDim.x * blockDim.x;
  for (int i = blockIdx.x * blockDim.x + threadIdx.x; i < n; i += stride) {
    if (isf32) dst[i] = f2bf(((const float*)src)[i]);
    else       dst[i] = ((const u16*)src)[i];
  }
}

// prep_bias: combined gemm bias (f32): b_ih + (n<512 ? b_hh : 0).
__global__ void prep_bias(const u16* __restrict__ bih, const u16* __restrict__ bhh,
                          float* __restrict__ bc, int n) {
  int i = blockIdx.x * blockDim.x + threadIdx.x;
  if (i >= n) return;
  int col = i % G3;
  float v = bf2f(bih[i]);
  if (col < 512) v += bf2f(bhh[i]);
  bc[i] = v;
}

// write_out: fp32 staging -> d_out in the harness's output dtype per count.
__global__ void write_out(const float* __restrict__ hNs, void* __restrict__ out,
                          int n, const int* __restrict__ cnt) {
  int i = blockIdx.x * blockDim.x + threadIdx.x;
  if (i >= n) return;
  if (*cnt > 64) ((float*)out)[i] = hNs[i];
  else           ((u16*)out)[i]   = f2bf(hNs[i]);
}

// ---------------------------------------------------------------------------
// gate_gemm: gates = A @ W^T + bias, written in scan-native layout:
//   gateX[dir][bg(4)][s(512)][jcol(256)][gate(3)][b_in(16)]  (u16)
// A: [SB][K] bf16. 128x128 tile / WG, BK=64, XOR-swizzled LDS.
// ---------------------------------------------------------------------------
__global__ __launch_bounds__(256)
void gate_gemm(const u16* __restrict__ A, const u16* __restrict__ W,
               const float* __restrict__ bias, u16* __restrict__ outg, int K) {
  const int m0  = blockIdx.x * 128;
  const int n0  = blockIdx.y * 128;
  const int dir = blockIdx.z;
  W    += (size_t)dir * G3 * K;
  bias += (size_t)dir * G3;
  outg += (size_t)dir * (size_t)SB * G3;

  __shared__ __align__(16) u16 lA[8192];   // 128 rows x 64 k, chunk-swizzled
  __shared__ __align__(16) u16 lB[8192];

  const int tid  = threadIdx.x;
  const int lane = tid & 63;
  const int wv   = tid >> 6;
  const int wm   = wv & 1, wn = wv >> 1;
  const int l15  = lane & 15, quad = lane >> 4;

  floatx4 acc[4][4] = {};   // [mt][nt]

  for (int k0 = 0; k0 < K; k0 += 64) {
    bf16x8 ra[4], rb[4];
#pragma unroll
    for (int i = 0; i < 4; ++i) {
      int c   = i * 256 + tid;          // chunk 0..1023
      int row = c >> 3;
      int kc  = (c & 7) ^ (row & 7);    // XOR-swizzled source chunk
      ra[i] = *(const bf16x8*)(A + (size_t)(m0 + row) * K + (k0 + kc * 8));
      rb[i] = *(const bf16x8*)(W + (size_t)(n0 + row) * K + (k0 + kc * 8));
    }
    __syncthreads();   // previous tile's LDS reads complete
#pragma unroll
    for (int i = 0; i < 4; ++i) {
      *(bf16x8*)(lA + (size_t)(i * 256 + tid) * 8) = ra[i];
      *(bf16x8*)(lB + (size_t)(i * 256 + tid) * 8) = rb[i];
    }
    __syncthreads();

#pragma unroll
    for (int kt = 0; kt < 2; ++kt) {
      bf16x8 af[4], bfr[4];
#pragma unroll
      for (int mt = 0; mt < 4; ++mt) {
        int row = wm * 64 + mt * 16 + l15;
        int ch  = row * 8 + ((kt * 4 + quad) ^ (row & 7));
        af[mt] = *(const bf16x8*)(lA + ch * 8);
      }
#pragma unroll
      for (int nt = 0; nt < 4; ++nt) {
        int row = wn * 64 + nt * 16 + l15;
        int ch  = row * 8 + ((kt * 4 + quad) ^ (row & 7));
        bfr[nt] = *(const bf16x8*)(lB + ch * 8);
      }
#pragma unroll
      for (int mt = 0; mt < 4; ++mt)
#pragma unroll
        for (int nt = 0; nt < 4; ++nt)
          acc[mt][nt] = __builtin_amdgcn_mfma_f32_16x16x32_bf16(
              af[mt], bfr[nt], acc[mt][nt], 0, 0, 0);
    }
  }

  // epilogue: C/D col(n)=l15, row(m)=quad*4+r. m = s*64 + b_global where
  // s = m0/64 + wm, bg = mt, b_in = quad*4+r.
  const int sIdx = (m0 >> 6) + wm;
#pragma unroll
  for (int nt = 0; nt < 4; ++nt) {
    int n    = n0 + wn * 64 + nt * 16 + l15;
    int g    = n >> 8, jc = n & 255;
    float bv = bias[n];
#pragma unroll
    for (int mt = 0; mt < 4; ++mt) {
      bf16x4 pk;
#pragma unroll
      for (int r = 0; r < 4; ++r) pk[r] = (short)f2bf(acc[mt][nt][r] + bv);
      *(bf16x4*)(outg + ((((size_t)mt * 512 + sIdx) * 256 + jc) * 3 + g) * 16 +
                 quad * 4) = pk;
    }
  }
}

// ---------------------------------------------------------------------------
// gru_scan v17 == v9/v15 EXACTLY (measured best: 773 us/layer; reproduced
// twice). Loop body untouched — no pragmas, no asm value ops, no hints.
// Fragility ledger (all measured worse, do NOT reintroduce):
//   v10/v13 cvt_pk+packed-h -> +33-38%; v11/v12 asm exp -> corruption;
//   v14 s_setprio -> +23%; v16 #pragma unroll 2 -> +12%.
// Structure: 44/48 weight frags register-resident (128 AGPR + 48 arch VGPR),
// 48 KB LDS (32 KB W_hn k-tail + 16 KB h double-buffer), one LDS-only
// barrier per step, gateX/layerOut vmcnt traffic in flight across it.
// ---------------------------------------------------------------------------
__global__ __launch_bounds__(512)
__attribute__((amdgpu_waves_per_eu(2, 2)))
void gru_scan(const u16* __restrict__ gateX,   // [2][4][512][256][3][16] bf16
              const u16* __restrict__ Whh,     // [2][768][256] (this layer)
              const u16* __restrict__ Bhh,     // [2][768]
              const u16* __restrict__ H0,      // [12][64][256] bf16 copy
              u16* __restrict__ layerOut,      // [SB][512] bf16
              float* __restrict__ hNs,         // fp32 staging [12][64][256]
              int layer) {
  const int dir = blockIdx.x & 1;
  const int bg  = blockIdx.x >> 1;
  const int tid = threadIdx.x;
  const int lane = tid & 63;
  const int wv   = tid >> 6;           // 0..7: owns hidden units [wv*32, wv*32+32)
  const int l15  = lane & 15, quad = lane >> 4;

  // 32 KB W_hn tail (k in [192,256)) + 16 KB h double-buffer = 48 KB
  __shared__ __align__(16) u16 wnL[16384];     // [kchunk(8)][n(256)][8]
  __shared__ __align__(16) u16 hb2[2][4096];   // [jchunk(32)][b(16)][8]

  const u16* Wd = Whh + (size_t)dir * G3 * HID;

  // --- prologue: W_hn k-tail -> LDS chunk-major (once) ---
#pragma unroll
  for (int i = 0; i < 4; ++i) {
    int ci = i * 512 + tid;            // 2048 bf16x8 chunks: 256 n x 8 kc
    int n  = ci >> 3;
    int kc = ci & 7;                   // local k-chunk; global = 24 + kc
    bf16x8 v = *(const bf16x8*)(Wd + (size_t)(512 + n) * HID + (24 + kc) * 8);
    *(bf16x8*)(wnL + kc * 2048 + n * 8) = v;
  }

  // --- stationary weights: r,z all kt (32 frags) + n kt=0..5 (12 frags) ---
  bf16x8 wrz[8][2][2];   // [kt][gate 0=r 1=z][nt]
  bf16x8 wn6[6][2];      // [kt 0..5][nt]
#pragma unroll
  for (int g = 0; g < 2; ++g)
#pragma unroll
    for (int nt = 0; nt < 2; ++nt) {
      int n = g * 256 + wv * 32 + nt * 16 + l15;
#pragma unroll
      for (int kt = 0; kt < 8; ++kt)
        wrz[kt][g][nt] = *(const bf16x8*)(Wd + (size_t)n * HID + kt * 32 + quad * 8);
    }
#pragma unroll
  for (int nt = 0; nt < 2; ++nt) {
    int n = 512 + wv * 32 + nt * 16 + l15;
#pragma unroll
    for (int kt = 0; kt < 6; ++kt)
      wn6[kt][nt] = *(const bf16x8*)(Wd + (size_t)n * HID + kt * 32 + quad * 8);
  }
#pragma unroll
  for (int kt = 0; kt < 8; ++kt)
#pragma unroll
    for (int g = 0; g < 2; ++g)
#pragma unroll
      for (int nt = 0; nt < 2; ++nt)
        asm volatile("" : "+v"(wrz[kt][g][nt]));
#pragma unroll
  for (int kt = 0; kt < 6; ++kt)
#pragma unroll
    for (int nt = 0; nt < 2; ++nt)
      asm volatile("" : "+v"(wn6[kt][nt]));

  float bhn[2];
#pragma unroll
  for (int nt = 0; nt < 2; ++nt)
    bhn[nt] = bf2f(Bhh[dir * G3 + 512 + wv * 32 + nt * 16 + l15]);

  const int mrow = quad * 4;           // first of this lane's 4 batch rows
  const int b0   = bg * 16 + mrow;     // global batch row at r=0

  // loop-invariant LDS bases (u16 indices)
  const int afb = quad * 128 + l15 * 8;                 // + kt*512
  const int bnb = quad * 2048 + (wv * 32 + l15) * 8;    // + (kt-6)*8192, +nt*128
  int wb[2];                                            // gate write/read base
#pragma unroll
  for (int nt = 0; nt < 2; ++nt)
    wb[nt] = (wv * 4 + nt * 2 + (l15 >> 3)) * 128 + quad * 32 + (l15 & 7);

  // --- init h in LDS chunk-major ---
  {
    int row = tid >> 5, slot = tid & 31;   // row=batch, slot=j-chunk
    const u16* hp = H0 + ((size_t)(layer * 2 + dir) * NB + bg * 16 + row) * HID + slot * 8;
    *(bf16x8*)(&hb2[0][slot * 128 + row * 8]) = *(const bf16x8*)hp;
  }

  // --- gateX pointer: one base, imm offsets ---
  const long sstep = dir ? -(long)(256 * 3 * 16) : (long)(256 * 3 * 16);
  const u16* xb;
  {
    const int s0 = dir ? (S_LEN - 1) : 0;
    xb = gateX + (size_t)dir * SB * G3 +
         ((((size_t)bg * 512 + s0) * 256 + (wv * 32 + l15)) * 3) * 16 + quad * 4;
  }
  bf16x4 xp[3][2];
#pragma unroll
  for (int g = 0; g < 3; ++g)
#pragma unroll
    for (int nt = 0; nt < 2; ++nt)
      xp[g][nt] = *(const bf16x4*)(xb + nt * 768 + g * 16);
  xb += sstep;

  // layerOut cooperative-store pointer: iteration t>0 stores h_{t-1} at s(t-1)
  u16* loPtr;
  {
    int row = tid >> 5, slot = tid & 31;
    const int sFirst = dir ? (S_LEN - 1) : 0;
    loPtr = layerOut + ((size_t)sFirst * NB + bg * 16 + row) * 512 +
            dir * HID + slot * 8;
  }
  const long lostep = dir ? -(long)(NB * 512) : (long)(NB * 512);

  lds_barrier();   // W_hn tail + h visible to all waves

  for (int t = 0; t < S_LEN; ++t) {
    const int cur = t & 1, nxt = cur ^ 1;

    // consume xpre: r/z (bias folded by gemm) -> acc init; xn kept bf16
    floatx4 aR[2], aZ[2], aN[2];
    bf16x4 xn0 = xp[2][0], xn1 = xp[2][1];
#pragma unroll
    for (int nt = 0; nt < 2; ++nt)
#pragma unroll
      for (int r = 0; r < 4; ++r) {
        aR[nt][r] = bf2f((u16)xp[0][nt][r]);
        aZ[nt][r] = bf2f((u16)xp[1][nt][r]);
        aN[nt][r] = bhn[nt];
      }

    // next step's prefetch; stays in flight across the lds_barrier
#pragma unroll
    for (int g = 0; g < 3; ++g)
#pragma unroll
      for (int nt = 0; nt < 2; ++nt)
        xp[g][nt] = *(const bf16x4*)(xb + nt * 768 + g * 16);
    if (t < S_LEN - 1) xb += sstep;

    // h_prev scalar reads from hb2[cur] (same addresses the gate phase writes)
    u16 hp[2][4];
#pragma unroll
    for (int nt = 0; nt < 2; ++nt)
#pragma unroll
      for (int r = 0; r < 4; ++r)
        hp[nt][r] = hb2[cur][wb[nt] + r * 8];

    // one-step-delayed cooperative layerOut store: h_{t-1} -> s(t-1)
    if (t > 0) {
      int row = tid >> 5, slot = tid & 31;
      bf16x8 hv = *(const bf16x8*)(&hb2[cur][slot * 128 + row * 8]);
      *(bf16x8*)loPtr = hv;   // fire-and-forget
      loPtr += lostep;
    }

    // MFMA phase: r,z and n(kt<6) B-frags from regs; n(kt 6,7) from LDS
#pragma unroll
    for (int kt = 0; kt < 8; ++kt) {
      bf16x8 af = *(const bf16x8*)(&hb2[cur][afb + kt * 512]);
      bf16x8 bn0, bn1;
      if (kt < 6) {
        bn0 = wn6[kt][0];
        bn1 = wn6[kt][1];
      } else {
        bn0 = *(const bf16x8*)(wnL + bnb + (kt - 6) * 8192);
        bn1 = *(const bf16x8*)(wnL + bnb + (kt - 6) * 8192 + 128);
      }
      aR[0] = __builtin_amdgcn_mfma_f32_16x16x32_bf16(af, wrz[kt][0][0], aR[0], 0, 0, 0);
      aR[1] = __builtin_amdgcn_mfma_f32_16x16x32_bf16(af, wrz[kt][0][1], aR[1], 0, 0, 0);
      aZ[0] = __builtin_amdgcn_mfma_f32_16x16x32_bf16(af, wrz[kt][1][0], aZ[0], 0, 0, 0);
      aZ[1] = __builtin_amdgcn_mfma_f32_16x16x32_bf16(af, wrz[kt][1][1], aZ[1], 0, 0, 0);
      aN[0] = __builtin_amdgcn_mfma_f32_16x16x32_bf16(af, bn0,           aN[0], 0, 0, 0);
      aN[1] = __builtin_amdgcn_mfma_f32_16x16x32_bf16(af, bn1,           aN[1], 0, 0, 0);
    }

    // gate phase: on accumulator fragments; h_prev from hp (bf16 scalars)
#pragma unroll
    for (int nt = 0; nt < 2; ++nt) {
      const bf16x4 xn = nt ? xn1 : xn0;
#pragma unroll
      for (int r = 0; r < 4; ++r) {
        float rg = fsigmoid(aR[nt][r]);
        float zg = fsigmoid(aZ[nt][r]);
        float ng = ftanh(bf2f((u16)xn[r]) + rg * aN[nt][r]);
        float h0 = bf2f(hp[nt][r]);
        float hn = ng + zg * (h0 - ng);
        hb2[nxt][wb[nt] + r * 8] = f2bf(hn);
      }
    }

    lds_barrier();   // h[nxt] visible; vmcnt traffic stays in flight
  }

  // final layerOut store + hNs: h_{511} is in hb2[0] (t=511: nxt=0)
  {
    int row = tid >> 5, slot = tid & 31;
    const int sLast = dir ? 0 : (S_LEN - 1);
    bf16x8 hv = *(const bf16x8*)(&hb2[0][slot * 128 + row * 8]);
    *(bf16x8*)(layerOut + ((size_t)sLast * NB + bg * 16 + row) * 512 +
               dir * HID + slot * 8) = hv;
    float* dst = hNs + ((size_t)(layer * 2 + dir) * NB + bg * 16 + row) * HID + slot * 8;
    floatx4 v0, v1;
#pragma unroll
    for (int i = 0; i < 4; ++i) v0[i] = bf2f((u16)hv[i]);
#pragma unroll
    for (int i = 0; i < 4; ++i) v1[i] = bf2f((u16)hv[4 + i]);
    *(floatx4*)dst = v0;
    *((floatx4*)dst + 1) = v1;
  }
}

// ---------------------------------------------------------------------------
extern "C" void kernel_launch(void* const* d_in, const int* in_sizes, int n_in,
                              void* d_out, int out_size, void* d_ws, size_t ws_size,
                              hipStream_t stream) {
  (void)n_in; (void)ws_size;
  char* ws = (char*)d_ws;
  int*   flag  = (int*)ws;
  float* hNs   = (float*)(ws + 4096);
  float* biasC = (float*)(ws + 790528);
  u16*   h0C   = (u16*)(ws + (1u << 20));
  u16*   wih0C = h0C   + 196608;
  u16*   wihC  = wih0C + 196608;
  u16*   whhC  = wihC  + 3932160;
  u16*   bihC  = whhC  + 2359296;
  u16*   bhhC  = bihC  + 9216;
  u16*   gateX = (u16*)(ws + (16u  << 20));
  u16*   bufA  = (u16*)(ws + (112u << 20));
  u16*   bufB  = (u16*)(ws + (144u << 20));
  u16*   xC    = bufB;   // aliased; layer-0 gemm reads it before bufB written

  hipMemsetAsync(flag, 0, 4, stream);
  detect_fp32<<<64, 256, 0, stream>>>((const u16*)d_in[0], 262144, flag);

  CvtArgs a;
  a.src[0] = d_in[0]; a.dst[0] = xC;    a.n[0] = in_sizes[0];
  a.src[1] = d_in[1]; a.dst[1] = h0C;   a.n[1] = in_sizes[1];
  a.src[2] = d_in[2]; a.dst[2] = wih0C; a.n[2] = in_sizes[2];
  a.src[3] = d_in[3]; a.dst[3] = wihC;  a.n[3] = in_sizes[3];
  a.src[4] = d_in[4]; a.dst[4] = whhC;  a.n[4] = in_sizes[4];
  a.src[5] = d_in[5]; a.dst[5] = bihC;  a.n[5] = in_sizes[5];
  a.src[6] = d_in[6]; a.dst[6] = bhhC;  a.n[6] = in_sizes[6];
  cvt_all<<<dim3(512, 7), 256, 0, stream>>>(a, flag);

  prep_bias<<<36, 256, 0, stream>>>(bihC, bhhC, biasC, NLAYER * 2 * G3);

  for (int layer = 0; layer < NLAYER; ++layer) {
    const u16* inp = (layer == 0) ? xC : ((layer & 1) ? bufA : bufB);
    u16* outBuf    = (layer & 1) ? bufB : bufA;

    const int K = (layer == 0) ? 128 : 512;
    const u16* W = (layer == 0) ? wih0C
                                : (wihC + (size_t)(layer - 1) * 2 * G3 * 512);
    dim3 grid(256, 6, 2);
    gate_gemm<<<grid, 256, 0, stream>>>(inp, W, biasC + (size_t)layer * 2 * G3,
                                        gateX, K);
    gru_scan<<<8, 512, 0, stream>>>(gateX, whhC + (size_t)layer * 2 * G3 * HID,
                                    bhhC + (size_t)layer * 2 * G3, h0C,
                                    outBuf, hNs, layer);
  }
  write_out<<<(out_size + 255) / 256, 256, 0, stream>>>(hNs, d_out, out_size, flag);
}